// Round 1
// baseline (2294.594 us; speedup 1.0000x reference)
//
#include <hip/hip_runtime.h>
#include <math.h>

// DSQG attention: B=8, H=16, N=8192, HD=64, J=20 offsets, all fp32.
// Thread-per-position: idx = bh*N + n. k/v row for offset d = (idx-d)*64.
#define BB 8
#define HH 16
#define NLEN 8192
#define HD 64
#define JJ 20

__global__ __launch_bounds__(256) void dsqg_attn_kernel(
    const float* __restrict__ q,
    const float* __restrict__ k,
    const float* __restrict__ v,
    const float* __restrict__ pb,   // [J,H]
    const float* __restrict__ se,   // [J,HD]
    float* __restrict__ out)
{
    constexpr int D[JJ] = {1, 2, 3, 4, 5, 6, 7, 8, 9, 11, 13, 15, 16, 23, 32,
                           64, 128, 256, 512, 1024};
    const int idx = blockIdx.x * 256 + threadIdx.x;   // == bh*NLEN + n
    const int n = idx & (NLEN - 1);
    const int h = (idx >> 13) & (HH - 1);
    const float sc = 0.125f;  // 1/sqrt(64)

    // Load q row, pre-scaled. 64 VGPRs.
    const float4* qr = (const float4*)(q + (size_t)idx * HD);
    float4 qv[16];
#pragma unroll
    for (int c = 0; c < 16; ++c) {
        float4 t = qr[c];
        t.x *= sc; t.y *= sc; t.z *= sc; t.w *= sc;
        qv[c] = t;
    }

    // Pass 1: scores s_j = qs . (k[n-d] + se_j) + pb[j,h]
    float s[JJ];
#pragma unroll
    for (int j = 0; j < JJ; ++j) {
        if (n >= D[j]) {
            const float4* kr = (const float4*)(k + (size_t)(idx - D[j]) * HD);
            const float4* sr = (const float4*)(se + j * HD);
            float acc = 0.0f;
#pragma unroll
            for (int c = 0; c < 16; ++c) {
                float4 kv = kr[c];
                float4 sv = sr[c];
                acc = fmaf(qv[c].x, kv.x + sv.x, acc);
                acc = fmaf(qv[c].y, kv.y + sv.y, acc);
                acc = fmaf(qv[c].z, kv.z + sv.z, acc);
                acc = fmaf(qv[c].w, kv.w + sv.w, acc);
            }
            s[j] = acc + pb[j * HH + h];
        } else {
            s[j] = -1e30f;
        }
    }

    // Softmax over the 20 offsets (branchless validity; n==0 -> all zero)
    float m = -1e30f;
#pragma unroll
    for (int j = 0; j < JJ; ++j) {
        if (n >= D[j]) m = fmaxf(m, s[j]);
    }
    float denom = 0.0f;
    float e[JJ];
#pragma unroll
    for (int j = 0; j < JJ; ++j) {
        float ej = (n >= D[j]) ? __expf(s[j] - m) : 0.0f;
        e[j] = ej;
        denom += ej;
    }
    const float inv = 1.0f / fmaxf(denom, 1e-30f);

    // Pass 2: out = sum_j p_j * v[n - d_j]
    float4 o[16];
#pragma unroll
    for (int c = 0; c < 16; ++c) o[c] = make_float4(0.f, 0.f, 0.f, 0.f);
#pragma unroll
    for (int j = 0; j < JJ; ++j) {
        if (n >= D[j]) {
            const float p = e[j] * inv;
            const float4* vr = (const float4*)(v + (size_t)(idx - D[j]) * HD);
#pragma unroll
            for (int c = 0; c < 16; ++c) {
                float4 vv = vr[c];
                o[c].x = fmaf(p, vv.x, o[c].x);
                o[c].y = fmaf(p, vv.y, o[c].y);
                o[c].z = fmaf(p, vv.z, o[c].z);
                o[c].w = fmaf(p, vv.w, o[c].w);
            }
        }
    }

    float4* outr = (float4*)(out + (size_t)idx * HD);
#pragma unroll
    for (int c = 0; c < 16; ++c) outr[c] = o[c];
}

extern "C" void kernel_launch(void* const* d_in, const int* in_sizes, int n_in,
                              void* d_out, int out_size, void* d_ws, size_t ws_size,
                              hipStream_t stream) {
    const float* q  = (const float*)d_in[0];
    const float* k  = (const float*)d_in[1];
    const float* v  = (const float*)d_in[2];
    const float* pb = (const float*)d_in[3];  // [J,H]
    const float* se = (const float*)d_in[4];  // [J,HD]
    float* out = (float*)d_out;

    const int total = BB * HH * NLEN;         // 1,048,576 positions
    dim3 grid(total / 256), block(256);
    dsqg_attn_kernel<<<grid, block, 0, stream>>>(q, k, v, pb, se, out);
}